// Round 7
// baseline (581.358 us; speedup 1.0000x reference)
//
#include <hip/hip_runtime.h>

// Problem constants (fixed by setup_inputs)
#define Bsz 4
#define Cc  512
#define C2  1024
#define H0c 192
#define Hh  48
#define Nn  2304   // 48*48
#define HNh 8
#define HD  64
#define Hs  25
#define Ms  625    // 25*25

typedef const float* fp;
typedef _Float16 f16;
typedef __attribute__((ext_vector_type(8))) _Float16 f16x8;
typedef __attribute__((ext_vector_type(4))) _Float16 f16x4;
typedef __attribute__((ext_vector_type(4))) float    f32x4;

// ======================= K1: fused front kernel =======================
// blocks [0, 4608):        ds-transpose  x -> xt f16 [b][2304][512]
// blocks [4608, 5888):     sr1 (2x2 dw s2 p1 + BN + ReLU) x -> kv1t f16 [b][625][512]
// blocks [5888, 6912):     weight cvt f32->f16 -> wh [q_w 262144][sr2_w 262144][kv_w 524288]
__global__ __launch_bounds__(256) void k_front(
    fp __restrict__ x, f16* __restrict__ xt, f16* __restrict__ kv1t,
    fp __restrict__ w1, fp g, fp bb, fp bm, fp bv,
    fp __restrict__ q_w, fp __restrict__ sr2_w, fp __restrict__ kv_w,
    f16* __restrict__ wh)
{
    __shared__ float tile[32][33];
    const int t = threadIdx.x;
    int bid = blockIdx.x;

    if (bid < 4608) {
        // ---- ds-transpose: s: n (2304), r: c (512) ----
        const int b  = bid / 1152;
        const int yi = (bid / 72) % 16;
        const int xi = bid % 72;
        const int s0 = xi * 32, r0 = yi * 32;
        const float* xb = x + (size_t)b * Cc * H0c * H0c;
        #pragma unroll
        for (int p = 0; p < 4; p++) {
            int e = t + p * 256; int i = e >> 5, j = e & 31;
            int c = r0 + i, n = s0 + j;
            tile[i][j] = xb[((size_t)c * H0c + (n / Hh) * 4) * H0c + (n % Hh) * 4];
        }
        __syncthreads();
        #pragma unroll
        for (int p = 0; p < 4; p++) {
            int e = t + p * 256; int oi = e >> 5, oj = e & 31;
            xt[((size_t)b * Nn + s0 + oi) * Cc + r0 + oj] = (f16)tile[oj][oi];
        }
    } else if (bid < 5888) {
        // ---- sr1 + transpose: s: n (625), r: c (512); reads x directly ----
        bid -= 4608;
        const int b  = bid / 320;
        const int yi = (bid / 20) % 16;
        const int xi = bid % 20;
        const int s0 = xi * 32, r0 = yi * 32;
        #pragma unroll
        for (int p = 0; p < 4; p++) {
            int e = t + p * 256; int i = e >> 5, j = e & 31;
            int c = r0 + i, n = s0 + j;
            float v = 0.f;
            if (n < Ms) {
                int ho = n / Hs, wo = n % Hs;
                const float* src = x + (size_t)(b * Cc + c) * H0c * H0c;
                float acc = 0.f;
                #pragma unroll
                for (int di = 0; di < 2; di++) {
                    int ih = ho * 2 - 1 + di;
                    if (ih < 0 || ih >= Hh) continue;
                    #pragma unroll
                    for (int dj = 0; dj < 2; dj++) {
                        int iw = wo * 2 - 1 + dj;
                        if (iw < 0 || iw >= Hh) continue;
                        acc += w1[c * 4 + di * 2 + dj] * src[(size_t)(ih * 4) * H0c + iw * 4];
                    }
                }
                float sc = g[c] * rsqrtf(bv[c] + 1e-5f);
                v = fmaxf((acc - bm[c]) * sc + bb[c], 0.f);
            }
            tile[i][j] = v;
        }
        __syncthreads();
        #pragma unroll
        for (int p = 0; p < 4; p++) {
            int e = t + p * 256; int oi = e >> 5, oj = e & 31;
            if (s0 + oi < Ms)
                kv1t[((size_t)b * Ms + s0 + oi) * Cc + r0 + oj] = (f16)tile[oj][oi];
        }
    } else {
        // ---- weight conversion, 1024 blocks x 256 thr x 4 f32 ----
        bid -= 5888;
        int i4 = (bid * 256 + t) * 4;       // < 1048576; segment boundaries %4 == 0
        float4 v;
        if (i4 < 262144)      v = *(const float4*)&q_w[i4];
        else if (i4 < 524288) v = *(const float4*)&sr2_w[i4 - 262144];
        else                  v = *(const float4*)&kv_w[i4 - 524288];
        f16x4 h; h[0] = (f16)v.x; h[1] = (f16)v.y; h[2] = (f16)v.z; h[3] = (f16)v.w;
        *(f16x4*)&wh[i4] = h;
    }
}

// ---------------- K3: fused 3x3 dwconv s1 p1 + bias + residual + transpose ----------------
// kv2 f32 [b][512][625] -> kv3t f16 [b][625][512]
__global__ __launch_bounds__(256) void k_lct(const float* __restrict__ kv2,
                                             fp __restrict__ w, fp __restrict__ lb,
                                             f16* __restrict__ kv3t) {
    __shared__ float tile[32][33];
    const int b = blockIdx.z;
    const int s0 = blockIdx.x * 32, r0 = blockIdx.y * 32;   // s: n (625), r: c (512)
    const int t = threadIdx.x;
    #pragma unroll
    for (int p = 0; p < 4; p++) {
        int e = t + p * 256; int i = e >> 5, j = e & 31;
        int c = r0 + i, n = s0 + j;
        float v = 0.f;
        if (n < Ms) {
            int ho = n / Hs, wo = n % Hs;
            const float* src = kv2 + ((size_t)b * Cc + c) * Ms;
            float acc = 0.f;
            #pragma unroll
            for (int di = 0; di < 3; di++) {
                int ih = ho - 1 + di;
                if (ih < 0 || ih >= Hs) continue;
                #pragma unroll
                for (int dj = 0; dj < 3; dj++) {
                    int iw = wo - 1 + dj;
                    if (iw < 0 || iw >= Hs) continue;
                    acc += w[c * 9 + di * 3 + dj] * src[ih * Hs + iw];
                }
            }
            v = acc + lb[c] + src[n];
        }
        tile[i][j] = v;
    }
    __syncthreads();
    #pragma unroll
    for (int p = 0; p < 4; p++) {
        int e = t + p * 256; int oi = e >> 5, oj = e & 31;
        if (s0 + oi < Ms)
            kv3t[((size_t)b * Ms + s0 + oi) * Cc + r0 + oj] = (f16)tile[oj][oi];
    }
}

// ---------------- shared MFMA GEMM body: Y[b][o][n] = sum_c W[o][c] * Xt[b][n][c] --------
// T14 async-split: next K-tile loaded into regs BEFORE current tile's MFMA phase.
__device__ __forceinline__ void gemm_body(
    const f16* __restrict__ W, const f16* __restrict__ Xt,
    float* __restrict__ Yf, f16* __restrict__ Yt, f16* __restrict__ Vt,
    const int Md, const int Nd, const int NtRows, const int mode, const float oscale,
    fp __restrict__ bias,
    fp __restrict__ bn_g, fp __restrict__ bn_b, fp __restrict__ bn_m, fp __restrict__ bn_v,
    const int bx, const int by, const int bz, f16* sA, f16* sB)
{
    const int b  = bz;
    const int m0 = by * 128, n0 = bx * 128;
    const int t = threadIdx.x;
    const int lane = t & 63, w = t >> 6;
    const int lm = lane & 15, q = lane >> 4;
    const int wm = w >> 1, wn = w & 1;
    const f16* Xb = Xt + (size_t)b * Nd * 512;

    const int sr = t >> 1, shh = (t & 1) * 32;           // staging row / k-half
    const f16* wrow = W + (size_t)(m0 + sr) * 512 + shh;
    const bool okB  = (n0 + sr) < Nd;
    const f16* xrow = Xb + (size_t)(n0 + sr) * 512 + shh;
    f16* dstA = &sA[sr * 80 + shh];
    f16* dstB = &sB[sr * 80 + shh];

    f32x4 acc[4][4];
    #pragma unroll
    for (int i = 0; i < 4; i++)
        #pragma unroll
        for (int j = 0; j < 4; j++)
            #pragma unroll
            for (int r = 0; r < 4; r++) acc[i][j][r] = 0.f;

    f16x8 ra[4], rb[4];
    // prologue: load k0 = 0
    #pragma unroll
    for (int i = 0; i < 4; i++) {
        ra[i] = *(const f16x8*)&wrow[i * 8];
        if (okB) rb[i] = *(const f16x8*)&xrow[i * 8];
        else     for (int z = 0; z < 8; z++) rb[i][z] = (f16)0.f;
    }

    for (int k0 = 0; k0 < 512; k0 += 64) {
        // write current regs to LDS
        #pragma unroll
        for (int i = 0; i < 4; i++) {
            *(f16x8*)&dstA[i * 8] = ra[i];
            *(f16x8*)&dstB[i * 8] = rb[i];
        }
        __syncthreads();
        // issue next-tile loads early (hidden under ds_read + MFMA)
        if (k0 + 64 < 512) {
            const f16* wn_ = wrow + k0 + 64;
            const f16* xn_ = xrow + k0 + 64;
            #pragma unroll
            for (int i = 0; i < 4; i++) {
                ra[i] = *(const f16x8*)&wn_[i * 8];
                if (okB) rb[i] = *(const f16x8*)&xn_[i * 8];
            }
        }
        #pragma unroll
        for (int ks = 0; ks < 2; ks++) {
            f16x8 af[4], bf[4];
            #pragma unroll
            for (int i = 0; i < 4; i++)
                af[i] = *(const f16x8*)&sA[(wm * 64 + i * 16 + lm) * 80 + ks * 32 + q * 8];
            #pragma unroll
            for (int j = 0; j < 4; j++)
                bf[j] = *(const f16x8*)&sB[(wn * 64 + j * 16 + lm) * 80 + ks * 32 + q * 8];
            #pragma unroll
            for (int i = 0; i < 4; i++)
                #pragma unroll
                for (int j = 0; j < 4; j++)
                    acc[i][j] = __builtin_amdgcn_mfma_f32_16x16x32_f16(af[i], bf[j], acc[i][j], 0, 0, 0);
        }
        __syncthreads();
    }

    // epilogue: D layout col=lane&15 (n), row=q*4+reg (o)
    #pragma unroll
    for (int i = 0; i < 4; i++) {
        int ob = m0 + wm * 64 + i * 16 + q * 4;       // + reg
        float badd[4], bsc[4], bsh[4];
        #pragma unroll
        for (int r = 0; r < 4; r++) {
            int o = ob + r;
            badd[r] = bias ? bias[o] : 0.f;
            if (bn_g) { bsc[r] = bn_g[o] * rsqrtf(bn_v[o] + 1e-5f); bsh[r] = bn_b[o] - bn_m[o] * bsc[r]; }
            else      { bsc[r] = 1.f; bsh[r] = 0.f; }
        }
        #pragma unroll
        for (int j = 0; j < 4; j++) {
            int n = n0 + wn * 64 + j * 16 + lm;
            f32x4 a = acc[i][j];
            if (mode == 0) {
                if (n < Nd) {
                    #pragma unroll
                    for (int r = 0; r < 4; r++)
                        Yf[((size_t)b * Md + ob + r) * Nd + n] = (a[r] + badd[r]) * bsc[r] + bsh[r];
                }
            } else if (mode == 1 || (mode == 2 && ob < 512)) {
                // rows >= 625 in mode 2 hold finite bias-only values, masked in attention
                f16x4 h;
                #pragma unroll
                for (int r = 0; r < 4; r++) h[r] = (f16)((a[r] + badd[r]) * oscale);
                int hh = ob >> 6, d0 = ob & 63;
                *(f16x4*)&Yt[((size_t)(b * 8 + hh) * NtRows + n) * 64 + d0] = h;
            } else { // mode 2, v-half -> Vt f16 [b*512 + o'][640], zero-pad cols >= 625
                #pragma unroll
                for (int r = 0; r < 4; r++) {
                    float val = (n < Nd) ? (a[r] + badd[r]) : 0.f;
                    Vt[((size_t)b * Cc + (ob + r - 512)) * 640 + n] = (f16)val;
                }
            }
        }
    }
}

// ---------------- K4: single-job GEMM (kv projection), 3D grid ----------------
__global__ __launch_bounds__(256) void k_gemm_mfma(
    const f16* __restrict__ W, const f16* __restrict__ Xt,
    float* __restrict__ Yf, f16* __restrict__ Yt, f16* __restrict__ Vt,
    const int Md, const int Nd, const int NtRows, const int mode, const float oscale,
    fp __restrict__ bias,
    fp __restrict__ bn_g, fp __restrict__ bn_b, fp __restrict__ bn_m, fp __restrict__ bn_v)
{
    __shared__ f16 sA[128 * 80];
    __shared__ f16 sB[128 * 80];
    gemm_body(W, Xt, Yf, Yt, Vt, Md, Nd, NtRows, mode, oscale,
              bias, bn_g, bn_b, bn_m, bn_v,
              blockIdx.x, blockIdx.y, blockIdx.z, sA, sB);
}

// ---------------- K2: dual-job GEMM (q-proj 288 blocks || sr2-proj 80 blocks) -------------
__global__ __launch_bounds__(256) void k_gemm2(
    const f16* __restrict__ W0, const f16* __restrict__ X0, f16* __restrict__ Yt0,
    const float osc0, fp __restrict__ bias0,
    const f16* __restrict__ W1, const f16* __restrict__ X1, float* __restrict__ Yf1,
    fp g1, fp b1, fp m1, fp v1)
{
    __shared__ f16 sA[128 * 80];
    __shared__ f16 sB[128 * 80];
    int bid = blockIdx.x;
    if (bid < 288) {
        // q projection: Md=512, Nd=2304, mode 1 (grid 18 x 4 x 4)
        int bx = bid % 18, by = (bid / 18) % 4, bz = bid / 72;
        gemm_body(W0, X0, nullptr, Yt0, nullptr, Cc, Nn, Nn, 1, osc0,
                  bias0, nullptr, nullptr, nullptr, nullptr, bx, by, bz, sA, sB);
    } else {
        // sr2 projection: Md=512, Nd=625, mode 0 + BN (grid 5 x 4 x 4)
        bid -= 288;
        int bx = bid % 5, by = (bid / 5) % 4, bz = bid / 20;
        gemm_body(W1, X1, Yf1, nullptr, nullptr, Cc, Ms, 0, 0, 1.f,
                  nullptr, g1, b1, m1, v1, bx, by, bz, sA, sB);
    }
}

// ---------------- K5: MFMA flash attention + full-line fused 4x upsample ----------------
// Qt f16 [bh][2304][64] (pre-scaled by 0.125); Kt f16 [bh][640][64] (rows>=625 masked);
// Vt f16 [bh*64 + d][640] (cols>=625 zero)  ->  out f32 [b][512][192][192]
// 1D grid 1152, XCD-chunked swizzle (1152%8==0): blocks sharing one bh's K/V land on
// the same XCD -> K/V stay L2-local. Exact skip-rescale: when no lane's chunk-max
// exceeds the running max, alpha==1.0 exactly and the O/m updates are identity ops.
__global__ __launch_bounds__(256) void k_attn_mfma(
    const f16* __restrict__ Qt, const f16* __restrict__ Kt,
    const f16* __restrict__ Vt, float* __restrict__ out)
{
    __shared__ __align__(16) unsigned char smem[30720];
    f16* sK = (f16*)smem;                   // [64][80]  10240 B   (K: [key][d])
    f16* sV = (f16*)(smem + 10240);         // [64][80]  10240 B   (V: [d][key])
    f16* sP4 = (f16*)(smem + 20480);        // [4][16*80] 10240 B  (per-wave P)
    float* sO = (float*)smem;               // [64][68]  17408 B   (epilogue only)

    // bijective XCD-chunked swizzle: nwg=1152, 8 XCDs, 144 blocks/XCD chunk
    const int swz = (blockIdx.x & 7) * 144 + (blockIdx.x >> 3);
    const int bh = swz / 36;
    const int n0 = (swz % 36) * 64;
    int t = threadIdx.x, w = t >> 6, lane = t & 63;
    int lm = lane & 15, q = lane >> 4;
    f16* sPw = sP4 + w * (16 * 80);

    f16x8 qf[2];
    {
        const f16* qrow = Qt + ((size_t)bh * Nn + n0 + w * 16 + lm) * 64;
        qf[0] = *(const f16x8*)&qrow[q * 8];
        qf[1] = *(const f16x8*)&qrow[32 + q * 8];
    }

    f32x4 od[4];
    #pragma unroll
    for (int dt = 0; dt < 4; dt++)
        #pragma unroll
        for (int r = 0; r < 4; r++) od[dt][r] = 0.f;
    float mold[4], lold[4];
    #pragma unroll
    for (int r = 0; r < 4; r++) { mold[r] = -1e30f; lold[r] = 0.f; }

    int kr = t >> 2, kc = t & 3;
    const f16* kbase = Kt + (size_t)bh * 640 * 64;
    const f16* vbase = Vt + (size_t)bh * 64 * 640;

    for (int mc = 0; mc < 640; mc += 64) {
        {   // stage K [key][d] and V [d][key]
            const f16* ksrc = kbase + (size_t)(mc + kr) * 64;
            *(f16x8*)&sK[kr * 80 + kc * 8]      = *(const f16x8*)&ksrc[kc * 8];
            *(f16x8*)&sK[kr * 80 + 32 + kc * 8] = *(const f16x8*)&ksrc[32 + kc * 8];
            const f16* vsrc = vbase + (size_t)kr * 640 + mc;
            *(f16x8*)&sV[kr * 80 + kc * 8]      = *(const f16x8*)&vsrc[kc * 8];
            *(f16x8*)&sV[kr * 80 + 32 + kc * 8] = *(const f16x8*)&vsrc[32 + kc * 8];
        }
        __syncthreads();

        // scores S = Q K^T (scale pre-folded into Qt)
        f32x4 sc4[4];
        #pragma unroll
        for (int j = 0; j < 4; j++)
            #pragma unroll
            for (int r = 0; r < 4; r++) sc4[j][r] = 0.f;
        #pragma unroll
        for (int ks = 0; ks < 2; ks++) {
            #pragma unroll
            for (int j = 0; j < 4; j++) {
                f16x8 kf = *(const f16x8*)&sK[(j * 16 + lm) * 80 + ks * 32 + q * 8];
                sc4[j] = __builtin_amdgcn_mfma_f32_16x16x32_f16(qf[ks], kf, sc4[j], 0, 0, 0);
            }
        }

        // online softmax; row r = q*4+reg, cols j*16+lm. Mask only in the last chunk.
        const bool lastc = (mc >= 576);
        #pragma unroll
        for (int reg = 0; reg < 4; reg++) {
            float mx;
            if (lastc) {
                mx = -1e30f;
                #pragma unroll
                for (int j = 0; j < 4; j++) {
                    float s = sc4[j][reg];
                    if (576 + j * 16 + lm >= Ms) s = -1e30f;
                    sc4[j][reg] = s;
                    mx = fmaxf(mx, s);
                }
            } else {
                mx = fmaxf(fmaxf(sc4[0][reg], sc4[1][reg]),
                           fmaxf(sc4[2][reg], sc4[3][reg]));
            }
            #pragma unroll
            for (int off = 1; off < 16; off <<= 1) mx = fmaxf(mx, __shfl_xor(mx, off));
            // exact skip-rescale: if no lane's mx exceeds its running max, then
            // mnew == mold and alpha == exp(0) == 1.0 exactly -> skip identity updates.
            const bool noresc = __all((int)(mx <= mold[reg]));
            float alpha = 1.f;
            if (!noresc) {
                float mnew = fmaxf(mold[reg], mx);
                alpha = __expf(mold[reg] - mnew);
                mold[reg] = mnew;
                #pragma unroll
                for (int dt = 0; dt < 4; dt++) od[dt][reg] *= alpha;
            }
            float rs = 0.f;
            #pragma unroll
            for (int j = 0; j < 4; j++) {
                float p = __expf(sc4[j][reg] - mold[reg]);
                sc4[j][reg] = p;
                rs += p;
            }
            #pragma unroll
            for (int off = 1; off < 16; off <<= 1) rs += __shfl_xor(rs, off);
            lold[reg] = lold[reg] * alpha + rs;   // alpha==1 on skip: fma(l,1,rs)=l+rs exact
            #pragma unroll
            for (int j = 0; j < 4; j++)
                sPw[(q * 4 + reg) * 80 + j * 16 + lm] = (f16)sc4[j][reg];
        }

        // O += P V : A=P[qrow][key], B=V^T[key][d] (sV holds [d][key])
        #pragma unroll
        for (int ks = 0; ks < 2; ks++) {
            f16x8 pa = *(const f16x8*)&sPw[lm * 80 + ks * 32 + q * 8];
            #pragma unroll
            for (int dt = 0; dt < 4; dt++) {
                f16x8 vf = *(const f16x8*)&sV[(dt * 16 + lm) * 80 + ks * 32 + q * 8];
                od[dt] = __builtin_amdgcn_mfma_f32_16x16x32_f16(pa, vf, od[dt], 0, 0, 0);
            }
        }
        __syncthreads();   // also guards sK/sV/sP before epilogue reuse as sO
    }

    // ---- epilogue: normalize -> sO[c][n] (stride 68: 2-way-free banks) ----
    float inv[4];
    #pragma unroll
    for (int r = 0; r < 4; r++) inv[r] = 1.f / lold[r];
    #pragma unroll
    for (int dt = 0; dt < 4; dt++) {
        f32x4 o;
        #pragma unroll
        for (int r = 0; r < 4; r++) o[r] = od[dt][r] * inv[r];
        *(f32x4*)&sO[(dt * 16 + lm) * 68 + w * 16 + q * 4] = o;   // 16B-aligned
    }
    __syncthreads();

    // ---- write pass: full-line 4x4 nearest upsample directly to out ----
    const int bq = bh >> 3, hch = (bh & 7) * 64;
    const int nl = lane;
    const int n  = n0 + nl;
    const int orow = (n / Hh) * 4, ocol = (n % Hh) * 4;
    #pragma unroll
    for (int it = 0; it < 16; it++) {
        int c = w * 16 + it;                       // 4 warps x 16 iters = 64 channels
        float s = sO[c * 68 + nl];
        float* oc = out + ((size_t)(bq * Cc + hch + c) * H0c + orow) * H0c + ocol;
        float4 pk = make_float4(s, s, s, s);
        #pragma unroll
        for (int ii = 0; ii < 4; ii++)
            *(float4*)&oc[ii * H0c] = pk;
    }
}

extern "C" void kernel_launch(void* const* d_in, const int* in_sizes, int n_in,
                              void* d_out, int out_size, void* d_ws, size_t ws_size,
                              hipStream_t stream) {
    (void)in_sizes; (void)n_in; (void)out_size; (void)ws_size;
    fp x     = (fp)d_in[0];
    fp q_w   = (fp)d_in[1];
    fp q_b   = (fp)d_in[2];
    fp kv_w  = (fp)d_in[3];
    fp kv_b  = (fp)d_in[4];
    fp sr1_w = (fp)d_in[5];
    fp bn1_g = (fp)d_in[6];
    fp bn1_b = (fp)d_in[7];
    fp bn1_m = (fp)d_in[8];
    fp bn1_v = (fp)d_in[9];
    fp sr2_w = (fp)d_in[10];
    fp bn2_g = (fp)d_in[11];
    fp bn2_b = (fp)d_in[12];
    fp bn2_m = (fp)d_in[13];
    fp bn2_v = (fp)d_in[14];
    fp lc_w  = (fp)d_in[15];
    fp lc_b  = (fp)d_in[16];
    float* out = (float*)d_out;

    // workspace layout (f32 units), peak 9,113,600 f32 = 36.5 MB
    float* ws   = (float*)d_ws;
    f16*   xt   = (f16*)ws;
    f16*   kv1t = (f16*)(ws + 2359296);
    f16*   wh   = (f16*)(ws + 2999296);
    float* kv2  = ws + 3523584;
    f16*   Qt   = (f16*)(ws + 4803584);
    f16*   Kt   = (f16*)(ws + 7162880);
    f16*   vt   = (f16*)(ws + 7818240);
    f16*   kv3t = (f16*)(ws + 8473600);

    // L1. front: ds-transpose (4608) + sr1+transpose (1280) + weight cvt (1024)
    k_front<<<6912, 256, 0, stream>>>(x, xt, kv1t, sr1_w, bn1_g, bn1_b, bn1_m, bn1_v,
                                      q_w, sr2_w, kv_w, wh);
    // L2. q projection (288 blocks) || sr2 projection + BN (80 blocks)
    k_gemm2<<<368, 256, 0, stream>>>(wh, xt, Qt, 0.125f, q_b,
                                     wh + 262144, kv1t, kv2, bn2_g, bn2_b, bn2_m, bn2_v);
    // L3. lc (3x3 dw + bias + residual) + transpose
    k_lct<<<dim3(20, 16, Bsz), 256, 0, stream>>>(kv2, lc_w, lc_b, kv3t);
    // L4. kv projection -> Kt (per-head f16) + vt (f16, zero-padded cols)
    k_gemm_mfma<<<dim3(5, 8, Bsz), 256, 0, stream>>>(wh + 524288, kv3t, nullptr, Kt, vt,
        C2, Ms, 640, 2, 1.f, kv_b, nullptr, nullptr, nullptr, nullptr);
    // L5. attention + full-line fused upsample -> out (XCD-swizzled 1D grid)
    k_attn_mfma<<<1152, 256, 0, stream>>>(Qt, Kt, vt, out);
}

// Round 8
// 576.693 us; speedup vs baseline: 1.0081x; 1.0081x over previous
//
#include <hip/hip_runtime.h>

// Problem constants (fixed by setup_inputs)
#define Bsz 4
#define Cc  512
#define C2  1024
#define H0c 192
#define Hh  48
#define Nn  2304   // 48*48
#define HNh 8
#define HD  64
#define Hs  25
#define Ms  625    // 25*25

typedef const float* fp;
typedef _Float16 f16;
typedef __attribute__((ext_vector_type(8))) _Float16 f16x8;
typedef __attribute__((ext_vector_type(4))) _Float16 f16x4;
typedef __attribute__((ext_vector_type(4))) float    f32x4;

// ======================= K1: fused front kernel =======================
// blocks [0, 4608):        ds-transpose  x -> xt f16 [b][2304][512]
// blocks [4608, 5888):     sr1 (2x2 dw s2 p1 + BN + ReLU) x -> kv1t f16 [b][625][512]
// blocks [5888, 6912):     weight cvt f32->f16 -> wh [q_w 262144][sr2_w 262144][kv_w 524288]
__global__ __launch_bounds__(256) void k_front(
    fp __restrict__ x, f16* __restrict__ xt, f16* __restrict__ kv1t,
    fp __restrict__ w1, fp g, fp bb, fp bm, fp bv,
    fp __restrict__ q_w, fp __restrict__ sr2_w, fp __restrict__ kv_w,
    f16* __restrict__ wh)
{
    __shared__ float tile[32][33];
    const int t = threadIdx.x;
    int bid = blockIdx.x;

    if (bid < 4608) {
        // ---- ds-transpose: s: n (2304), r: c (512) ----
        const int b  = bid / 1152;
        const int yi = (bid / 72) % 16;
        const int xi = bid % 72;
        const int s0 = xi * 32, r0 = yi * 32;
        const float* xb = x + (size_t)b * Cc * H0c * H0c;
        #pragma unroll
        for (int p = 0; p < 4; p++) {
            int e = t + p * 256; int i = e >> 5, j = e & 31;
            int c = r0 + i, n = s0 + j;
            tile[i][j] = xb[((size_t)c * H0c + (n / Hh) * 4) * H0c + (n % Hh) * 4];
        }
        __syncthreads();
        #pragma unroll
        for (int p = 0; p < 4; p++) {
            int e = t + p * 256; int oi = e >> 5, oj = e & 31;
            xt[((size_t)b * Nn + s0 + oi) * Cc + r0 + oj] = (f16)tile[oj][oi];
        }
    } else if (bid < 5888) {
        // ---- sr1 + transpose: s: n (625), r: c (512); reads x directly ----
        bid -= 4608;
        const int b  = bid / 320;
        const int yi = (bid / 20) % 16;
        const int xi = bid % 20;
        const int s0 = xi * 32, r0 = yi * 32;
        #pragma unroll
        for (int p = 0; p < 4; p++) {
            int e = t + p * 256; int i = e >> 5, j = e & 31;
            int c = r0 + i, n = s0 + j;
            float v = 0.f;
            if (n < Ms) {
                int ho = n / Hs, wo = n % Hs;
                const float* src = x + (size_t)(b * Cc + c) * H0c * H0c;
                float acc = 0.f;
                #pragma unroll
                for (int di = 0; di < 2; di++) {
                    int ih = ho * 2 - 1 + di;
                    if (ih < 0 || ih >= Hh) continue;
                    #pragma unroll
                    for (int dj = 0; dj < 2; dj++) {
                        int iw = wo * 2 - 1 + dj;
                        if (iw < 0 || iw >= Hh) continue;
                        acc += w1[c * 4 + di * 2 + dj] * src[(size_t)(ih * 4) * H0c + iw * 4];
                    }
                }
                float sc = g[c] * rsqrtf(bv[c] + 1e-5f);
                v = fmaxf((acc - bm[c]) * sc + bb[c], 0.f);
            }
            tile[i][j] = v;
        }
        __syncthreads();
        #pragma unroll
        for (int p = 0; p < 4; p++) {
            int e = t + p * 256; int oi = e >> 5, oj = e & 31;
            if (s0 + oi < Ms)
                kv1t[((size_t)b * Ms + s0 + oi) * Cc + r0 + oj] = (f16)tile[oj][oi];
        }
    } else {
        // ---- weight conversion, 1024 blocks x 256 thr x 4 f32 ----
        bid -= 5888;
        int i4 = (bid * 256 + t) * 4;       // < 1048576; segment boundaries %4 == 0
        float4 v;
        if (i4 < 262144)      v = *(const float4*)&q_w[i4];
        else if (i4 < 524288) v = *(const float4*)&sr2_w[i4 - 262144];
        else                  v = *(const float4*)&kv_w[i4 - 524288];
        f16x4 h; h[0] = (f16)v.x; h[1] = (f16)v.y; h[2] = (f16)v.z; h[3] = (f16)v.w;
        *(f16x4*)&wh[i4] = h;
    }
}

// ---------------- K3: fused 3x3 dwconv s1 p1 + bias + residual + transpose ----------------
// kv2 f32 [b][512][625] -> kv3t f16 [b][625][512]
__global__ __launch_bounds__(256) void k_lct(const float* __restrict__ kv2,
                                             fp __restrict__ w, fp __restrict__ lb,
                                             f16* __restrict__ kv3t) {
    __shared__ float tile[32][33];
    const int b = blockIdx.z;
    const int s0 = blockIdx.x * 32, r0 = blockIdx.y * 32;   // s: n (625), r: c (512)
    const int t = threadIdx.x;
    #pragma unroll
    for (int p = 0; p < 4; p++) {
        int e = t + p * 256; int i = e >> 5, j = e & 31;
        int c = r0 + i, n = s0 + j;
        float v = 0.f;
        if (n < Ms) {
            int ho = n / Hs, wo = n % Hs;
            const float* src = kv2 + ((size_t)b * Cc + c) * Ms;
            float acc = 0.f;
            #pragma unroll
            for (int di = 0; di < 3; di++) {
                int ih = ho - 1 + di;
                if (ih < 0 || ih >= Hs) continue;
                #pragma unroll
                for (int dj = 0; dj < 3; dj++) {
                    int iw = wo - 1 + dj;
                    if (iw < 0 || iw >= Hs) continue;
                    acc += w[c * 9 + di * 3 + dj] * src[ih * Hs + iw];
                }
            }
            v = acc + lb[c] + src[n];
        }
        tile[i][j] = v;
    }
    __syncthreads();
    #pragma unroll
    for (int p = 0; p < 4; p++) {
        int e = t + p * 256; int oi = e >> 5, oj = e & 31;
        if (s0 + oi < Ms)
            kv3t[((size_t)b * Ms + s0 + oi) * Cc + r0 + oj] = (f16)tile[oj][oi];
    }
}

// ---------------- shared MFMA GEMM body: Y[b][o][n] = sum_c W[o][c] * Xt[b][n][c] --------
// T14 async-split: next K-tile loaded into regs BEFORE current tile's MFMA phase.
__device__ __forceinline__ void gemm_body(
    const f16* __restrict__ W, const f16* __restrict__ Xt,
    float* __restrict__ Yf, f16* __restrict__ Yt, f16* __restrict__ Vt,
    const int Md, const int Nd, const int NtRows, const int mode, const float oscale,
    fp __restrict__ bias,
    fp __restrict__ bn_g, fp __restrict__ bn_b, fp __restrict__ bn_m, fp __restrict__ bn_v,
    const int bx, const int by, const int bz, f16* sA, f16* sB)
{
    const int b  = bz;
    const int m0 = by * 128, n0 = bx * 128;
    const int t = threadIdx.x;
    const int lane = t & 63, w = t >> 6;
    const int lm = lane & 15, q = lane >> 4;
    const int wm = w >> 1, wn = w & 1;
    const f16* Xb = Xt + (size_t)b * Nd * 512;

    const int sr = t >> 1, shh = (t & 1) * 32;           // staging row / k-half
    const f16* wrow = W + (size_t)(m0 + sr) * 512 + shh;
    const bool okB  = (n0 + sr) < Nd;
    const f16* xrow = Xb + (size_t)(n0 + sr) * 512 + shh;
    f16* dstA = &sA[sr * 80 + shh];
    f16* dstB = &sB[sr * 80 + shh];

    f32x4 acc[4][4];
    #pragma unroll
    for (int i = 0; i < 4; i++)
        #pragma unroll
        for (int j = 0; j < 4; j++)
            #pragma unroll
            for (int r = 0; r < 4; r++) acc[i][j][r] = 0.f;

    f16x8 ra[4], rb[4];
    // prologue: load k0 = 0
    #pragma unroll
    for (int i = 0; i < 4; i++) {
        ra[i] = *(const f16x8*)&wrow[i * 8];
        if (okB) rb[i] = *(const f16x8*)&xrow[i * 8];
        else     for (int z = 0; z < 8; z++) rb[i][z] = (f16)0.f;
    }

    for (int k0 = 0; k0 < 512; k0 += 64) {
        // write current regs to LDS
        #pragma unroll
        for (int i = 0; i < 4; i++) {
            *(f16x8*)&dstA[i * 8] = ra[i];
            *(f16x8*)&dstB[i * 8] = rb[i];
        }
        __syncthreads();
        // issue next-tile loads early (hidden under ds_read + MFMA)
        if (k0 + 64 < 512) {
            const f16* wn_ = wrow + k0 + 64;
            const f16* xn_ = xrow + k0 + 64;
            #pragma unroll
            for (int i = 0; i < 4; i++) {
                ra[i] = *(const f16x8*)&wn_[i * 8];
                if (okB) rb[i] = *(const f16x8*)&xn_[i * 8];
            }
        }
        #pragma unroll
        for (int ks = 0; ks < 2; ks++) {
            f16x8 af[4], bf[4];
            #pragma unroll
            for (int i = 0; i < 4; i++)
                af[i] = *(const f16x8*)&sA[(wm * 64 + i * 16 + lm) * 80 + ks * 32 + q * 8];
            #pragma unroll
            for (int j = 0; j < 4; j++)
                bf[j] = *(const f16x8*)&sB[(wn * 64 + j * 16 + lm) * 80 + ks * 32 + q * 8];
            #pragma unroll
            for (int i = 0; i < 4; i++)
                #pragma unroll
                for (int j = 0; j < 4; j++)
                    acc[i][j] = __builtin_amdgcn_mfma_f32_16x16x32_f16(af[i], bf[j], acc[i][j], 0, 0, 0);
        }
        __syncthreads();
    }

    // epilogue: D layout col=lane&15 (n), row=q*4+reg (o)
    #pragma unroll
    for (int i = 0; i < 4; i++) {
        int ob = m0 + wm * 64 + i * 16 + q * 4;       // + reg
        float badd[4], bsc[4], bsh[4];
        #pragma unroll
        for (int r = 0; r < 4; r++) {
            int o = ob + r;
            badd[r] = bias ? bias[o] : 0.f;
            if (bn_g) { bsc[r] = bn_g[o] * rsqrtf(bn_v[o] + 1e-5f); bsh[r] = bn_b[o] - bn_m[o] * bsc[r]; }
            else      { bsc[r] = 1.f; bsh[r] = 0.f; }
        }
        #pragma unroll
        for (int j = 0; j < 4; j++) {
            int n = n0 + wn * 64 + j * 16 + lm;
            f32x4 a = acc[i][j];
            if (mode == 0) {
                if (n < Nd) {
                    #pragma unroll
                    for (int r = 0; r < 4; r++)
                        Yf[((size_t)b * Md + ob + r) * Nd + n] = (a[r] + badd[r]) * bsc[r] + bsh[r];
                }
            } else if (mode == 1 || (mode == 2 && ob < 512)) {
                // rows >= 625 in mode 2 hold finite bias-only values, masked in attention
                f16x4 h;
                #pragma unroll
                for (int r = 0; r < 4; r++) h[r] = (f16)((a[r] + badd[r]) * oscale);
                int hh = ob >> 6, d0 = ob & 63;
                *(f16x4*)&Yt[((size_t)(b * 8 + hh) * NtRows + n) * 64 + d0] = h;
            } else { // mode 2, v-half -> Vt f16 [b*512 + o'][640], zero-pad cols >= 625
                #pragma unroll
                for (int r = 0; r < 4; r++) {
                    float val = (n < Nd) ? (a[r] + badd[r]) : 0.f;
                    Vt[((size_t)b * Cc + (ob + r - 512)) * 640 + n] = (f16)val;
                }
            }
        }
    }
}

// ---------------- K4: single-job GEMM (kv projection), 3D grid ----------------
__global__ __launch_bounds__(256) void k_gemm_mfma(
    const f16* __restrict__ W, const f16* __restrict__ Xt,
    float* __restrict__ Yf, f16* __restrict__ Yt, f16* __restrict__ Vt,
    const int Md, const int Nd, const int NtRows, const int mode, const float oscale,
    fp __restrict__ bias,
    fp __restrict__ bn_g, fp __restrict__ bn_b, fp __restrict__ bn_m, fp __restrict__ bn_v)
{
    __shared__ f16 sA[128 * 80];
    __shared__ f16 sB[128 * 80];
    gemm_body(W, Xt, Yf, Yt, Vt, Md, Nd, NtRows, mode, oscale,
              bias, bn_g, bn_b, bn_m, bn_v,
              blockIdx.x, blockIdx.y, blockIdx.z, sA, sB);
}

// ---------------- K2: dual-job GEMM (q-proj 288 blocks || sr2-proj 80 blocks) -------------
__global__ __launch_bounds__(256) void k_gemm2(
    const f16* __restrict__ W0, const f16* __restrict__ X0, f16* __restrict__ Yt0,
    const float osc0, fp __restrict__ bias0,
    const f16* __restrict__ W1, const f16* __restrict__ X1, float* __restrict__ Yf1,
    fp g1, fp b1, fp m1, fp v1)
{
    __shared__ f16 sA[128 * 80];
    __shared__ f16 sB[128 * 80];
    int bid = blockIdx.x;
    if (bid < 288) {
        // q projection: Md=512, Nd=2304, mode 1 (grid 18 x 4 x 4)
        int bx = bid % 18, by = (bid / 18) % 4, bz = bid / 72;
        gemm_body(W0, X0, nullptr, Yt0, nullptr, Cc, Nn, Nn, 1, osc0,
                  bias0, nullptr, nullptr, nullptr, nullptr, bx, by, bz, sA, sB);
    } else {
        // sr2 projection: Md=512, Nd=625, mode 0 + BN (grid 5 x 4 x 4)
        bid -= 288;
        int bx = bid % 5, by = (bid / 5) % 4, bz = bid / 20;
        gemm_body(W1, X1, Yf1, nullptr, nullptr, Cc, Ms, 0, 0, 1.f,
                  nullptr, g1, b1, m1, v1, bx, by, bz, sA, sB);
    }
}

// ---------------- K5: MFMA flash attention + full-line fused 4x upsample ----------------
// Qt f16 [bh][2304][64] (pre-scaled by 0.125); Kt f16 [bh][640][64] (rows>=625 masked);
// Vt f16 [bh*64 + d][640] (cols>=625 zero)  ->  out f32 [b][512][192][192]
// T14 async-stage: chunk mc+1's K/V global loads are issued right after the barrier,
// hiding L2 latency under QK^T/softmax/PV; ds_write of held regs at top of next chunk.
__global__ __launch_bounds__(256) void k_attn_mfma(
    const f16* __restrict__ Qt, const f16* __restrict__ Kt,
    const f16* __restrict__ Vt, float* __restrict__ out)
{
    __shared__ __align__(16) unsigned char smem[30720];
    f16* sK = (f16*)smem;                   // [64][80]  10240 B   (K: [key][d])
    f16* sV = (f16*)(smem + 10240);         // [64][80]  10240 B   (V: [d][key])
    f16* sP4 = (f16*)(smem + 20480);        // [4][16*80] 10240 B  (per-wave P)
    float* sO = (float*)smem;               // [64][68]  17408 B   (epilogue only)

    int bh = blockIdx.y;
    int n0 = blockIdx.x * 64;
    int t = threadIdx.x, w = t >> 6, lane = t & 63;
    int lm = lane & 15, q = lane >> 4;
    f16* sPw = sP4 + w * (16 * 80);

    f16x8 qf[2];
    {
        const f16* qrow = Qt + ((size_t)bh * Nn + n0 + w * 16 + lm) * 64;
        qf[0] = *(const f16x8*)&qrow[q * 8];
        qf[1] = *(const f16x8*)&qrow[32 + q * 8];
    }

    f32x4 od[4];
    #pragma unroll
    for (int dt = 0; dt < 4; dt++)
        #pragma unroll
        for (int r = 0; r < 4; r++) od[dt][r] = 0.f;
    float mold[4], lold[4];
    #pragma unroll
    for (int r = 0; r < 4; r++) { mold[r] = -1e30f; lold[r] = 0.f; }

    const int kr = t >> 2, kc = t & 3;
    const f16* kbase = Kt + (size_t)bh * 640 * 64;
    const f16* vbase = Vt + (size_t)bh * 64 * 640;

    // T14 prologue: load chunk 0's K/V into regs
    f16x8 kreg[2], vreg[2];
    {
        const f16* ksrc = kbase + (size_t)kr * 64;
        kreg[0] = *(const f16x8*)&ksrc[kc * 8];
        kreg[1] = *(const f16x8*)&ksrc[32 + kc * 8];
        const f16* vsrc = vbase + (size_t)kr * 640;
        vreg[0] = *(const f16x8*)&vsrc[kc * 8];
        vreg[1] = *(const f16x8*)&vsrc[32 + kc * 8];
    }

    for (int mc = 0; mc < 640; mc += 64) {
        // ds_write the held regs (K [key][d], V [d][key])
        *(f16x8*)&sK[kr * 80 + kc * 8]      = kreg[0];
        *(f16x8*)&sK[kr * 80 + 32 + kc * 8] = kreg[1];
        *(f16x8*)&sV[kr * 80 + kc * 8]      = vreg[0];
        *(f16x8*)&sV[kr * 80 + 32 + kc * 8] = vreg[1];
        __syncthreads();

        // issue next chunk's loads early (latency hides under compute below)
        if (mc + 64 < 640) {
            const f16* ksrc = kbase + (size_t)(mc + 64 + kr) * 64;
            kreg[0] = *(const f16x8*)&ksrc[kc * 8];
            kreg[1] = *(const f16x8*)&ksrc[32 + kc * 8];
            const f16* vsrc = vbase + (size_t)kr * 640 + mc + 64;
            vreg[0] = *(const f16x8*)&vsrc[kc * 8];
            vreg[1] = *(const f16x8*)&vsrc[32 + kc * 8];
        }

        // scores S = Q K^T (scale pre-folded into Qt)
        f32x4 sc4[4];
        #pragma unroll
        for (int j = 0; j < 4; j++)
            #pragma unroll
            for (int r = 0; r < 4; r++) sc4[j][r] = 0.f;
        #pragma unroll
        for (int ks = 0; ks < 2; ks++) {
            #pragma unroll
            for (int j = 0; j < 4; j++) {
                f16x8 kf = *(const f16x8*)&sK[(j * 16 + lm) * 80 + ks * 32 + q * 8];
                sc4[j] = __builtin_amdgcn_mfma_f32_16x16x32_f16(qf[ks], kf, sc4[j], 0, 0, 0);
            }
        }

        // online softmax; row r = q*4+reg, cols j*16+lm. Mask only in the last chunk.
        const bool lastc = (mc >= 576);
        #pragma unroll
        for (int reg = 0; reg < 4; reg++) {
            float mx;
            if (lastc) {
                mx = -1e30f;
                #pragma unroll
                for (int j = 0; j < 4; j++) {
                    float s = sc4[j][reg];
                    if (576 + j * 16 + lm >= Ms) s = -1e30f;
                    sc4[j][reg] = s;
                    mx = fmaxf(mx, s);
                }
            } else {
                mx = fmaxf(fmaxf(sc4[0][reg], sc4[1][reg]),
                           fmaxf(sc4[2][reg], sc4[3][reg]));
            }
            #pragma unroll
            for (int off = 1; off < 16; off <<= 1) mx = fmaxf(mx, __shfl_xor(mx, off));
            float mnew = fmaxf(mold[reg], mx);
            float alpha = __expf(mold[reg] - mnew);
            float rs = 0.f;
            #pragma unroll
            for (int j = 0; j < 4; j++) {
                float p = __expf(sc4[j][reg] - mnew);
                sc4[j][reg] = p;
                rs += p;
            }
            #pragma unroll
            for (int off = 1; off < 16; off <<= 1) rs += __shfl_xor(rs, off);
            lold[reg] = lold[reg] * alpha + rs;
            mold[reg] = mnew;
            #pragma unroll
            for (int dt = 0; dt < 4; dt++) od[dt][reg] *= alpha;
            #pragma unroll
            for (int j = 0; j < 4; j++)
                sPw[(q * 4 + reg) * 80 + j * 16 + lm] = (f16)sc4[j][reg];
        }

        // O += P V : A=P[qrow][key], B=V^T[key][d] (sV holds [d][key])
        #pragma unroll
        for (int ks = 0; ks < 2; ks++) {
            f16x8 pa = *(const f16x8*)&sPw[lm * 80 + ks * 32 + q * 8];
            #pragma unroll
            for (int dt = 0; dt < 4; dt++) {
                f16x8 vf = *(const f16x8*)&sV[(dt * 16 + lm) * 80 + ks * 32 + q * 8];
                od[dt] = __builtin_amdgcn_mfma_f32_16x16x32_f16(pa, vf, od[dt], 0, 0, 0);
            }
        }
        __syncthreads();   // also guards sK/sV/sP before next ds_write / epilogue reuse
    }

    // ---- epilogue: normalize -> sO[c][n] (stride 68: 2-way-free banks) ----
    float inv[4];
    #pragma unroll
    for (int r = 0; r < 4; r++) inv[r] = 1.f / lold[r];
    #pragma unroll
    for (int dt = 0; dt < 4; dt++) {
        f32x4 o;
        #pragma unroll
        for (int r = 0; r < 4; r++) o[r] = od[dt][r] * inv[r];
        *(f32x4*)&sO[(dt * 16 + lm) * 68 + w * 16 + q * 4] = o;   // 16B-aligned
    }
    __syncthreads();

    // ---- write pass: full-line 4x4 nearest upsample directly to out ----
    const int bq = bh >> 3, hch = (bh & 7) * 64;
    const int nl = lane;
    const int n  = n0 + nl;
    const int orow = (n / Hh) * 4, ocol = (n % Hh) * 4;
    #pragma unroll
    for (int it = 0; it < 16; it++) {
        int c = w * 16 + it;                       // 4 warps x 16 iters = 64 channels
        float s = sO[c * 68 + nl];
        float* oc = out + ((size_t)(bq * Cc + hch + c) * H0c + orow) * H0c + ocol;
        float4 pk = make_float4(s, s, s, s);
        #pragma unroll
        for (int ii = 0; ii < 4; ii++)
            *(float4*)&oc[ii * H0c] = pk;
    }
}

extern "C" void kernel_launch(void* const* d_in, const int* in_sizes, int n_in,
                              void* d_out, int out_size, void* d_ws, size_t ws_size,
                              hipStream_t stream) {
    (void)in_sizes; (void)n_in; (void)out_size; (void)ws_size;
    fp x     = (fp)d_in[0];
    fp q_w   = (fp)d_in[1];
    fp q_b   = (fp)d_in[2];
    fp kv_w  = (fp)d_in[3];
    fp kv_b  = (fp)d_in[4];
    fp sr1_w = (fp)d_in[5];
    fp bn1_g = (fp)d_in[6];
    fp bn1_b = (fp)d_in[7];
    fp bn1_m = (fp)d_in[8];
    fp bn1_v = (fp)d_in[9];
    fp sr2_w = (fp)d_in[10];
    fp bn2_g = (fp)d_in[11];
    fp bn2_b = (fp)d_in[12];
    fp bn2_m = (fp)d_in[13];
    fp bn2_v = (fp)d_in[14];
    fp lc_w  = (fp)d_in[15];
    fp lc_b  = (fp)d_in[16];
    float* out = (float*)d_out;

    // workspace layout (f32 units), peak 9,113,600 f32 = 36.5 MB
    float* ws   = (float*)d_ws;
    f16*   xt   = (f16*)ws;
    f16*   kv1t = (f16*)(ws + 2359296);
    f16*   wh   = (f16*)(ws + 2999296);
    float* kv2  = ws + 3523584;
    f16*   Qt   = (f16*)(ws + 4803584);
    f16*   Kt   = (f16*)(ws + 7162880);
    f16*   vt   = (f16*)(ws + 7818240);
    f16*   kv3t = (f16*)(ws + 8473600);

    // L1. front: ds-transpose (4608) + sr1+transpose (1280) + weight cvt (1024)
    k_front<<<6912, 256, 0, stream>>>(x, xt, kv1t, sr1_w, bn1_g, bn1_b, bn1_m, bn1_v,
                                      q_w, sr2_w, kv_w, wh);
    // L2. q projection (288 blocks) || sr2 projection + BN (80 blocks)
    k_gemm2<<<368, 256, 0, stream>>>(wh, xt, Qt, 0.125f, q_b,
                                     wh + 262144, kv1t, kv2, bn2_g, bn2_b, bn2_m, bn2_v);
    // L3. lc (3x3 dw + bias + residual) + transpose
    k_lct<<<dim3(20, 16, Bsz), 256, 0, stream>>>(kv2, lc_w, lc_b, kv3t);
    // L4. kv projection -> Kt (per-head f16) + vt (f16, zero-padded cols)
    k_gemm_mfma<<<dim3(5, 8, Bsz), 256, 0, stream>>>(wh + 524288, kv3t, nullptr, Kt, vt,
        C2, Ms, 640, 2, 1.f, kv_b, nullptr, nullptr, nullptr, nullptr);
    // L5. attention + full-line fused upsample -> out (T14 async K/V staging)
    k_attn_mfma<<<dim3(Nn / 64, Bsz * HNh), 256, 0, stream>>>(Qt, Kt, vt, out);
}